// Round 8
// baseline (574.687 us; speedup 1.0000x reference)
//
#include <hip/hip_runtime.h>
#include <hip/hip_bf16.h>
#include <math.h>

#define D_MODEL 1024
#define SEQ 2048
#define BATCH 2
#define NH 16
#define DH 64
#define D_HID 4096
#define MTOT (BATCH*SEQ)   // 4096 rows
#define LOG2E 1.4426950408889634f

typedef __attribute__((ext_vector_type(8))) short bf16x8;
typedef __attribute__((ext_vector_type(4))) float f32x4;

__device__ __forceinline__ unsigned short f2bf(float f) {
    unsigned int u = __float_as_uint(f);
    u += 0x7FFF + ((u >> 16) & 1);     // round-to-nearest-even
    return (unsigned short)(u >> 16);
}

__device__ __forceinline__ float gelu_exact(float x) {
    return 0.5f * x * (1.0f + erff(x * 0.70710678118654752f));
}

// async global->LDS, 16 bytes per lane. LDS dest = wave-uniform base + lane*16.
__device__ __forceinline__ void gload16(const void* g, void* l) {
    __builtin_amdgcn_global_load_lds(
        (__attribute__((address_space(1))) void*)(g),
        (__attribute__((address_space(3))) void*)(l), 16, 0, 0);
}

// ---------------------------------------------------------------------------
// bf16 MFMA GEMM: BMx128 tile, BK=64 (two 32-K panels per stage), 4 waves,
// 16x16x32 MFMA, global_load_lds width 16, ONE barrier-pair per 64 K.
// A: bf16 [M][K] row-major.  Bt: bf16 [N][K] row-major (pre-transposed).
// EPI: 0 = fp32 out; 2 = bias+GELU -> bf16; 3 = bias -> Q,K scatter + V^T scatter
// ---------------------------------------------------------------------------
template<int EPI, int BM>
__global__ __launch_bounds__(256) void gemm_bf16(
    const unsigned short* __restrict__ A,
    const unsigned short* __restrict__ Bt,
    const float* __restrict__ bias,
    float* __restrict__ Cf,
    unsigned short* __restrict__ Cb,
    unsigned short* __restrict__ Qo,
    unsigned short* __restrict__ Ko,
    unsigned short* __restrict__ Vo,
    int N, int K, int nbx)
{
    constexpr int MF   = BM / 32;   // m-fragments per wave
    constexpr int NCHA = BM / 8;    // 1KB chunks in A tile
    constexpr int PCHA = BM / 16;   // chunks per A panel
    __shared__ unsigned short As[BM * 64];
    __shared__ unsigned short Bs[128 * 64];

    const int nwg = (int)gridDim.x;
    int bid = (int)blockIdx.x;
    bid = (bid & 7) * (nwg >> 3) + (bid >> 3);  // XCD-contiguous chunks (nwg%8==0)
    const int bx = bid % nbx;
    const int by = bid / nbx;

    const int tid = threadIdx.x;
    const int l   = tid & 63;
    const int w   = tid >> 6;
    const int wr  = w >> 1, wc = w & 1;
    const int fr  = l & 15, fg = l >> 4;
    const size_t row0 = (size_t)by * BM;
    const size_t col0 = (size_t)bx * 128;

    const int rsub = l >> 2;        // 0..15 row within 16-row chunk stripe
    const int csub = (l & 3) * 8;   // 0,8,16,24 col within 32-col panel

    f32x4 acc[MF][4] = {};

    for (int kk = 0; kk < K; kk += 64) {
        #pragma unroll
        for (int i = 0; i < NCHA / 4; ++i) {
            const int ch = i * 4 + w;
            const int p = ch / PCHA, j = ch % PCHA;
            gload16(A + (row0 + j * 16 + rsub) * K + kk + p * 32 + csub,
                    &As[ch * 512 + l * 8]);
        }
        #pragma unroll
        for (int i = 0; i < 4; ++i) {
            const int ch = i * 4 + w;
            const int p = ch >> 3, j = ch & 7;
            gload16(Bt + (col0 + j * 16 + rsub) * K + kk + p * 32 + csub,
                    &Bs[ch * 512 + l * 8]);
        }
        __syncthreads();

        #pragma unroll
        for (int ks = 0; ks < 2; ++ks) {
            bf16x8 af[MF], bfv[4];
            #pragma unroll
            for (int m = 0; m < MF; ++m)
                af[m] = *(const bf16x8*)&As[ks * BM * 32 + (wr * (BM / 2) + m * 16 + fr) * 32 + fg * 8];
            #pragma unroll
            for (int n = 0; n < 4; ++n)
                bfv[n] = *(const bf16x8*)&Bs[ks * 4096 + (wc * 64 + n * 16 + fr) * 32 + fg * 8];
            #pragma unroll
            for (int m = 0; m < MF; ++m)
                #pragma unroll
                for (int n = 0; n < 4; ++n)
                    acc[m][n] = __builtin_amdgcn_mfma_f32_16x16x32_bf16(
                        af[m], bfv[n], acc[m][n], 0, 0, 0);
        }
        __syncthreads();
    }

    // Epilogue. C/D layout: col = n*16 + (l&15), row = m*16 + (l>>4)*4 + j
    #pragma unroll
    for (int m = 0; m < MF; ++m) {
        #pragma unroll
        for (int n = 0; n < 4; ++n) {
            const int c = (int)col0 + wc * 64 + n * 16 + fr;
            const float badd = (EPI >= 2) ? bias[c] : 0.f;
            #pragma unroll
            for (int j = 0; j < 4; ++j) {
                const size_t r = row0 + wr * (BM / 2) + m * 16 + fg * 4 + j;
                float v = acc[m][n][j] + badd;
                if (EPI == 0) {
                    Cf[r * N + c] = v;
                } else if (EPI == 2) {
                    Cb[r * N + c] = f2bf(gelu_exact(v));
                } else {  // QKV scatter: Q,K -> [B*H][S][64]; V -> [B*H][64][S]
                    const int which = c >> 10;
                    const int h = (c >> 6) & 15;
                    const int d = c & 63;
                    const size_t bb = r >> 11;
                    const size_t s  = r & 2047;
                    if (which == 2)
                        Vo[((bb * NH + h) * 64 + d) * SEQ + s] = f2bf(v);
                    else {
                        unsigned short* dst = (which == 0) ? Qo : Ko;
                        dst[((bb * NH + h) * SEQ + s) * 64 + d] = f2bf(v);
                    }
                }
            }
        }
    }
}

// ---------------------------------------------------------------------------
// 256x256-tile 2-phase GEMM: 512 threads = 8 waves (2x4), per-wave 128x64 out,
// BK=64 (two 32-K panels), bias+GELU->bf16 epilogue (FFN1).
// LDS 64KB single-buffered; per-wave 64 MFMAs per barrier-pair.
// ---------------------------------------------------------------------------
__global__ __launch_bounds__(512) void gemm256(
    const unsigned short* __restrict__ A,
    const unsigned short* __restrict__ Bt,
    const float* __restrict__ bias,
    unsigned short* __restrict__ Cb,
    int N, int K, int nbx)
{
    __shared__ unsigned short As[2 * 256 * 32];   // [panel][row][32]
    __shared__ unsigned short Bs[2 * 256 * 32];

    const int nwg = (int)gridDim.x;
    int bid = (int)blockIdx.x;
    bid = (bid & 7) * (nwg >> 3) + (bid >> 3);
    const int bx = bid % nbx;
    const int by = bid / nbx;

    const int tid = threadIdx.x;
    const int l   = tid & 63;
    const int w   = tid >> 6;          // 0..7
    const int wr  = w >> 2, wc = w & 3;
    const int fr  = l & 15, fg = l >> 4;
    const size_t row0 = (size_t)by * 256;
    const size_t col0 = (size_t)bx * 256;

    const int rsub = l >> 2;
    const int csub = (l & 3) * 8;

    f32x4 acc[8][4] = {};

    for (int kk = 0; kk < K; kk += 64) {
        #pragma unroll
        for (int i = 0; i < 4; ++i) {
            const int ch = i * 8 + w;          // 0..31
            const int p = ch >> 4, j = ch & 15;
            gload16(A + (row0 + j * 16 + rsub) * K + kk + p * 32 + csub,
                    &As[ch * 512 + l * 8]);
            gload16(Bt + (col0 + j * 16 + rsub) * K + kk + p * 32 + csub,
                    &Bs[ch * 512 + l * 8]);
        }
        __syncthreads();

        #pragma unroll
        for (int ks = 0; ks < 2; ++ks) {
            bf16x8 af[8], bfv[4];
            #pragma unroll
            for (int m = 0; m < 8; ++m)
                af[m] = *(const bf16x8*)&As[ks * 8192 + (wr * 128 + m * 16 + fr) * 32 + fg * 8];
            #pragma unroll
            for (int n = 0; n < 4; ++n)
                bfv[n] = *(const bf16x8*)&Bs[ks * 8192 + (wc * 64 + n * 16 + fr) * 32 + fg * 8];
            #pragma unroll
            for (int m = 0; m < 8; ++m)
                #pragma unroll
                for (int n = 0; n < 4; ++n)
                    acc[m][n] = __builtin_amdgcn_mfma_f32_16x16x32_bf16(
                        af[m], bfv[n], acc[m][n], 0, 0, 0);
        }
        __syncthreads();
    }

    #pragma unroll
    for (int m = 0; m < 8; ++m) {
        #pragma unroll
        for (int n = 0; n < 4; ++n) {
            const int c = (int)col0 + wc * 64 + n * 16 + fr;
            const float badd = bias[c];
            #pragma unroll
            for (int j = 0; j < 4; ++j) {
                const size_t r = row0 + wr * 128 + m * 16 + fg * 4 + j;
                Cb[r * N + c] = f2bf(gelu_exact(acc[m][n][j] + badd));
            }
        }
    }
}

// ---------------------------------------------------------------------------
// MFMA flash attention (causal), QBLK=64: 4 independent waves x 16 rows,
// K-tiles of 64. NO K/V LDS staging (K/V are L2-resident: 256KB/head, reused
// by 32 q-blocks) -> no __syncthreads in the k-loop, waves fully decoupled.
// K fragments read directly from Kh [B*H][S][64]; V from VTh [B*H][64][S].
// Q pre-scaled by log2(e)/8; exp2 softmax; T13 defer-max; T5 setprio.
// ---------------------------------------------------------------------------
__global__ __launch_bounds__(256) void attn_mfma(
    const unsigned short* __restrict__ Qh,   // [B*H][S][64] bf16 (pre-scaled)
    const unsigned short* __restrict__ Kh,   // [B*H][S][64] bf16
    const unsigned short* __restrict__ VTh,  // [B*H][64][S] bf16
    unsigned short* __restrict__ Ctx)        // [B][S][H*64] bf16
{
    __shared__ unsigned short Ps[4][16][72];

    const int tid  = threadIdx.x;
    const int lane = tid & 63;
    const int w    = tid >> 6;
    const int fr   = lane & 15, fg = lane >> 4;
    const int q0   = ((int)gridDim.x - 1 - (int)blockIdx.x) * 64;
    const int h    = blockIdx.y;
    const int b    = blockIdx.z;
    const size_t bh64 = ((size_t)(b * NH + h)) * SEQ * 64;

    const unsigned short* Kb  = Kh  + bh64;
    const unsigned short* VTb = VTh + bh64;

    // Q A-fragments for this wave's 16 rows
    const int qrow = q0 + w * 16 + fr;
    const bf16x8 qf0 = *(const bf16x8*)(Qh + bh64 + (size_t)qrow * 64 + fg * 8);
    const bf16x8 qf1 = *(const bf16x8*)(Qh + bh64 + (size_t)qrow * 64 + 32 + fg * 8);

    f32x4 o[4] = {};
    float mrow[4] = {-INFINITY, -INFINITY, -INFINITY, -INFINITY};
    float lrow[4] = {0.f, 0.f, 0.f, 0.f};

    const int ktmax = q0 >> 6;
    for (int kt = 0; kt <= ktmax; ++kt) {
        // K B-fragments direct from global (L2-hit)
        bf16x8 kf0[4], kf1[4];
        #pragma unroll
        for (int n = 0; n < 4; ++n) {
            const unsigned short* kp = Kb + (size_t)(kt * 64 + n * 16 + fr) * 64 + fg * 8;
            kf0[n] = *(const bf16x8*)kp;
            kf1[n] = *(const bf16x8*)(kp + 32);
        }

        // S = Q K^T  (C-layout: row q = fg*4+j, col kc = n*16+fr)
        f32x4 sf[4];
        __builtin_amdgcn_s_setprio(1);
        #pragma unroll
        for (int n = 0; n < 4; ++n) {
            f32x4 s = {0.f, 0.f, 0.f, 0.f};
            s = __builtin_amdgcn_mfma_f32_16x16x32_bf16(qf0, kf0[n], s, 0, 0, 0);
            s = __builtin_amdgcn_mfma_f32_16x16x32_bf16(qf1, kf1[n], s, 0, 0, 0);
            sf[n] = s;
        }
        __builtin_amdgcn_s_setprio(0);

        if (kt == ktmax) {  // diagonal tile: mask col > row
            #pragma unroll
            for (int n = 0; n < 4; ++n)
                #pragma unroll
                for (int j = 0; j < 4; ++j) {
                    const int colg = q0 + n * 16 + fr;
                    const int rowg = q0 + w * 16 + fg * 4 + j;
                    if (colg > rowg) sf[n][j] = -INFINITY;
                }
        }

        // per-row tile max (reduce across 16 fr lanes)
        float pm[4];
        #pragma unroll
        for (int j = 0; j < 4; ++j) {
            float v = fmaxf(fmaxf(sf[0][j], sf[1][j]), fmaxf(sf[2][j], sf[3][j]));
            #pragma unroll
            for (int off = 1; off < 16; off <<= 1)
                v = fmaxf(v, __shfl_xor(v, off, 64));
            pm[j] = v;
        }

        // V B-fragments issued here; latency hides under softmax VALU
        bf16x8 vb0[4], vb1[4];
        #pragma unroll
        for (int n = 0; n < 4; ++n) {
            const unsigned short* vp = VTb + (size_t)(n * 16 + fr) * SEQ + kt * 64 + fg * 8;
            vb0[n] = *(const bf16x8*)vp;
            vb1[n] = *(const bf16x8*)(vp + 32);
        }

        // T13 defer-max: skip rescale when no row grew by more than 8 (log2)
        int ok = 1;
        #pragma unroll
        for (int j = 0; j < 4; ++j)
            ok &= (pm[j] <= mrow[j] + 8.f) ? 1 : 0;
        if (!__all(ok)) {
            #pragma unroll
            for (int j = 0; j < 4; ++j) {
                const float mn = fmaxf(mrow[j], pm[j]);
                const float sc = exp2f(mrow[j] - mn);   // -inf -> 0
                mrow[j] = mn;
                lrow[j] *= sc;
                #pragma unroll
                for (int n = 0; n < 4; ++n)
                    o[n][j] *= sc;
            }
        }

        // P = exp2(S - m); accumulate l; P -> per-wave LDS bf16
        float ls[4] = {0.f, 0.f, 0.f, 0.f};
        #pragma unroll
        for (int n = 0; n < 4; ++n)
            #pragma unroll
            for (int j = 0; j < 4; ++j) {
                const float p = exp2f(sf[n][j] - mrow[j]);
                ls[j] += p;
                Ps[w][fg * 4 + j][n * 16 + fr] = f2bf(p);
            }
        #pragma unroll
        for (int j = 0; j < 4; ++j) {
            #pragma unroll
            for (int off = 1; off < 16; off <<= 1)
                ls[j] += __shfl_xor(ls[j], off, 64);
            lrow[j] += ls[j];
        }

        const bf16x8 pa0 = *(const bf16x8*)&Ps[w][fr][fg * 8];
        const bf16x8 pa1 = *(const bf16x8*)&Ps[w][fr][32 + fg * 8];

        // PV: O += P x V
        __builtin_amdgcn_s_setprio(1);
        #pragma unroll
        for (int n = 0; n < 4; ++n) {
            o[n] = __builtin_amdgcn_mfma_f32_16x16x32_bf16(pa0, vb0[n], o[n], 0, 0, 0);
            o[n] = __builtin_amdgcn_mfma_f32_16x16x32_bf16(pa1, vb1[n], o[n], 0, 0, 0);
        }
        __builtin_amdgcn_s_setprio(0);
    }

    // epilogue: normalize, write ctx bf16 [b][s][h*64+d]
    const size_t ob = (size_t)b * SEQ * D_MODEL + (size_t)h * 64;
    #pragma unroll
    for (int j = 0; j < 4; ++j) {
        const int rowg = q0 + w * 16 + fg * 4 + j;
        const float inv = 1.f / lrow[j];
        #pragma unroll
        for (int n = 0; n < 4; ++n)
            Ctx[ob + (size_t)rowg * D_MODEL + n * 16 + fr] = f2bf(o[n][j] * inv);
    }
}

// ---------------------------------------------------------------------------
// Fused residual + LayerNorm; optionally also emits bf16 copy for next GEMM.
// ---------------------------------------------------------------------------
template<bool WB>
__global__ __launch_bounds__(256) void ln_residual(
    const float* __restrict__ resid, const float* __restrict__ y,
    const float* __restrict__ g, const float* __restrict__ bta,
    float* __restrict__ outf, unsigned short* __restrict__ outb) {
    const int row = blockIdx.x;
    const int t4 = threadIdx.x * 4;
    const float4 v = *(const float4*)(y + (size_t)row * D_MODEL + t4);

    float s  = v.x + v.y + v.z + v.w;
    float s2 = v.x * v.x + v.y * v.y + v.z * v.z + v.w * v.w;
    #pragma unroll
    for (int off = 1; off < 64; off <<= 1) {
        s  += __shfl_xor(s, off, 64);
        s2 += __shfl_xor(s2, off, 64);
    }
    __shared__ float red[8];
    const int wave = threadIdx.x >> 6;
    if ((threadIdx.x & 63) == 0) { red[wave] = s; red[4 + wave] = s2; }
    __syncthreads();
    s  = red[0] + red[1] + red[2] + red[3];
    s2 = red[4] + red[5] + red[6] + red[7];

    const float mu  = s * (1.f / D_MODEL);
    const float var = s2 * (1.f / D_MODEL) - mu * mu;
    const float rstd = rsqrtf(var + 1e-5f);

    const float4 rr = *(const float4*)(resid + (size_t)row * D_MODEL + t4);
    const float4 gg = *(const float4*)(g + t4);
    const float4 bb = *(const float4*)(bta + t4);
    float4 o;
    o.x = rr.x + (v.x - mu) * rstd * gg.x + bb.x;
    o.y = rr.y + (v.y - mu) * rstd * gg.y + bb.y;
    o.z = rr.z + (v.z - mu) * rstd * gg.z + bb.z;
    o.w = rr.w + (v.w - mu) * rstd * gg.w + bb.w;
    *(float4*)(outf + (size_t)row * D_MODEL + t4) = o;
    if (WB) {
        uint2 pv;
        pv.x = (unsigned)f2bf(o.x) | ((unsigned)f2bf(o.y) << 16);
        pv.y = (unsigned)f2bf(o.z) | ((unsigned)f2bf(o.w) << 16);
        *(uint2*)(outb + (size_t)row * D_MODEL + t4) = pv;
    }
}

// ---------------------------------------------------------------------------
// Packing kernels
// ---------------------------------------------------------------------------
__global__ void pack_bf16(const float* __restrict__ in, unsigned short* __restrict__ out, int n) {
    const int i = (blockIdx.x * 256 + threadIdx.x) * 4;
    if (i + 3 >= n) { for (int k = i; k < n; ++k) out[k] = f2bf(in[k]); return; }
    const float4 v = *(const float4*)(in + i);
    uint2 pv;
    pv.x = (unsigned)f2bf(v.x) | ((unsigned)f2bf(v.y) << 16);
    pv.y = (unsigned)f2bf(v.z) | ((unsigned)f2bf(v.w) << 16);
    *(uint2*)(out + i) = pv;
}

__global__ void pack_bias(const float* __restrict__ bq, const float* __restrict__ bk,
                          const float* __restrict__ bv, float* __restrict__ outb) {
    const int i = blockIdx.x * 256 + threadIdx.x;   // 0..3071
    outb[i] = (i < 1024) ? bq[i] * (0.125f * LOG2E) : (i < 2048) ? bk[i - 1024] : bv[i - 2048];
}

// Four 1024x1024 fp32 [K][N] weights -> bf16 [N][K] transposed, fused launch.
__global__ __launch_bounds__(256) void transpose_pack4(
    const float* __restrict__ W0, const float* __restrict__ W1,
    const float* __restrict__ W2, const float* __restrict__ W3,
    unsigned short* __restrict__ Oqkv, unsigned short* __restrict__ Oo) {
    const int z = blockIdx.z;
    const float* W = (z == 0) ? W0 : (z == 1) ? W1 : (z == 2) ? W2 : W3;
    unsigned short* Out = (z == 3) ? Oo : (Oqkv + (size_t)z * 1024 * 1024);
    const float scale = (z == 0) ? 0.125f * LOG2E : 1.f;
    __shared__ float t[32][33];
    const int tx = threadIdx.x & 31, ty = threadIdx.x >> 5;  // ty 0..7
    const int k0 = blockIdx.y * 32, n0 = blockIdx.x * 32;
    #pragma unroll
    for (int i = 0; i < 4; ++i)
        t[ty + i * 8][tx] = W[(size_t)(k0 + ty + i * 8) * 1024 + n0 + tx];
    __syncthreads();
    #pragma unroll
    for (int i = 0; i < 4; ++i) {
        const int n = ty + i * 8;
        Out[(size_t)(n0 + n) * 1024 + k0 + tx] = f2bf(t[tx][n] * scale);
    }
}

// W fp32 [K][N] -> Out bf16 [N][K] (transposed).
__global__ __launch_bounds__(256) void transpose_pack(
    const float* __restrict__ W, unsigned short* __restrict__ Out, int K, int N) {
    __shared__ float t[32][33];
    const int tx = threadIdx.x & 31, ty = threadIdx.x >> 5;
    const int k0 = blockIdx.y * 32, n0 = blockIdx.x * 32;
    #pragma unroll
    for (int i = 0; i < 4; ++i)
        t[ty + i * 8][tx] = W[(size_t)(k0 + ty + i * 8) * N + n0 + tx];
    __syncthreads();
    #pragma unroll
    for (int i = 0; i < 4; ++i) {
        const int n = ty + i * 8;
        Out[(size_t)(n0 + n) * K + k0 + tx] = f2bf(t[tx][n]);
    }
}

// ---------------------------------------------------------------------------
extern "C" void kernel_launch(void* const* d_in, const int* in_sizes, int n_in,
                              void* d_out, int out_size, void* d_ws, size_t ws_size,
                              hipStream_t stream) {
    const float* x     = (const float*)d_in[0];
    const float* wq    = (const float*)d_in[1];
    const float* bq    = (const float*)d_in[2];
    const float* wk    = (const float*)d_in[3];
    const float* bk    = (const float*)d_in[4];
    const float* wv    = (const float*)d_in[5];
    const float* bv    = (const float*)d_in[6];
    const float* wo    = (const float*)d_in[7];
    const float* ln1_g = (const float*)d_in[8];
    const float* ln1_b = (const float*)d_in[9];
    const float* w1    = (const float*)d_in[10];
    const float* b1    = (const float*)d_in[11];
    const float* w2    = (const float*)d_in[12];
    const float* ln2_g = (const float*)d_in[13];
    const float* ln2_b = (const float*)d_in[14];
    float* out = (float*)d_out;

    char* base = (char*)d_ws;
    const size_t MB = 1 << 20;
    unsigned short* xb    = (unsigned short*)(base + 0 * MB);     // 8 MB
    unsigned short* WqkvT = (unsigned short*)(base + 8 * MB);     // 6 MB
    unsigned short* WoT   = (unsigned short*)(base + 14 * MB);    // 2 MB
    unsigned short* W1T   = (unsigned short*)(base + 16 * MB);    // 8 MB
    unsigned short* W2T   = (unsigned short*)(base + 24 * MB);    // 8 MB
    float*          bqkv  = (float*)        (base + 32 * MB);     // 12 KB
    unsigned short* Qh    = (unsigned short*)(base + 33 * MB);    // 8 MB
    unsigned short* Kh    = (unsigned short*)(base + 41 * MB);    // 8 MB
    unsigned short* VTh   = (unsigned short*)(base + 49 * MB);    // 8 MB [B*H][64][S]
    unsigned short* CTXb  = (unsigned short*)(base + 57 * MB);    // 8 MB
    float*          ATT   = (float*)        (base + 65 * MB);     // 16 MB
    float*          X1    = (float*)        (base + 81 * MB);     // 16 MB
    unsigned short* X1b   = (unsigned short*)(base + 97 * MB);    // 8 MB
    unsigned short* Hb    = (unsigned short*)(base + 105 * MB);   // 32 MB
    float*          FFN   = (float*)        (base + 65 * MB);     // reuse ATT

    const dim3 blk(256);

    // pack inputs/weights to bf16 (log2e*Q-scale folded into wq/bq)
    pack_bf16<<<4096, blk, 0, stream>>>(x, xb, MTOT * D_MODEL);
    pack_bias<<<12, blk, 0, stream>>>(bq, bk, bv, bqkv);
    transpose_pack4<<<dim3(32, 32, 4), blk, 0, stream>>>(wq, wk, wv, wo, WqkvT, WoT);
    transpose_pack<<<dim3(128, 32), blk, 0, stream>>>(w1, W1T, 1024, 4096);
    transpose_pack<<<dim3(32, 128), blk, 0, stream>>>(w2, W2T, 4096, 1024);

    // fused QKV projection -> Q,K [B*H][S][64]; V^T [B*H][64][S]  (768 blocks)
    gemm_bf16<3, 128><<<dim3(768), blk, 0, stream>>>(xb, WqkvT, bqkv, nullptr, nullptr,
                                                     Qh, Kh, VTh, 3072, 1024, 24);
    // causal MFMA flash attention (QBLK=64, no K/V staging) -> ctx bf16
    attn_mfma<<<dim3(SEQ / 64, NH, BATCH), blk, 0, stream>>>(Qh, Kh, VTh, CTXb);
    // output projection (fp32 out)   (BM=64: 512 blocks)
    gemm_bf16<0, 64><<<dim3(512), blk, 0, stream>>>(CTXb, WoT, nullptr, ATT, nullptr,
                                                    nullptr, nullptr, nullptr, 1024, 1024, 8);
    // x1 = x + LN(att)
    ln_residual<true><<<dim3(MTOT), blk, 0, stream>>>(x, ATT, ln1_g, ln1_b, X1, X1b);
    // FFN1: 256x256-tile 2-phase (256 blocks, 512 threads)
    gemm256<<<dim3(256), dim3(512), 0, stream>>>(X1b, W1T, b1, Hb, 4096, 1024, 16);
    gemm_bf16<0, 64><<<dim3(512), blk, 0, stream>>>(Hb, W2T, nullptr, FFN, nullptr,
                                                    nullptr, nullptr, nullptr, 1024, 4096, 8);
    // out = x1 + LN(ffn)
    ln_residual<false><<<dim3(MTOT), blk, 0, stream>>>(X1, FFN, ln2_g, ln2_b, out, nullptr);
}